// Round 1
// baseline (47.911 us; speedup 1.0000x reference)
//
#include <hip/hip_runtime.h>
#include <math.h>

constexpr int BS_   = 64;
constexpr int NTGT  = 5000;
constexpr int H0 = 160, H1 = 80, H2 = 40;
constexpr int HW0 = H0 * H0;          // 25600
constexpr int HW1 = H1 * H1;          // 6400
constexpr int HW2 = H2 * H2;          // 1600
constexpr int N0 = BS_ * HW0;         // 1,638,400
constexpr int N1 = BS_ * HW1;         // 409,600
constexpr int N2 = BS_ * HW2;         // 102,400
constexpr int NTOT = N0 + N1 + N2;    // 2,150,400
constexpr int BITS_WORDS = (N0 + N1 + N2) / 32;   // 67,200 words
constexpr int BITS_BYTES = BITS_WORDS * 4;        // 268,800 bytes

// block = 256 threads = 4 waves of 64
__device__ __forceinline__ float block_reduce_sum(float v) {
    // wave-64 butterfly
    #pragma unroll
    for (int off = 32; off > 0; off >>= 1)
        v += __shfl_down(v, off, 64);
    __shared__ float s[4];
    int lane = threadIdx.x & 63;
    int wid  = threadIdx.x >> 6;
    if (lane == 0) s[wid] = v;
    __syncthreads();
    if (threadIdx.x == 0) v = s[0] + s[1] + s[2] + s[3];
    return v; // valid on thread 0 only
}

// Pass 1: sum of t=0 BCE terms over all cells of all three levels,
// each level weighted by 1/N_level.
__global__ void base_sum_kernel(const float* __restrict__ p0,
                                const float* __restrict__ p1,
                                const float* __restrict__ p2,
                                float* __restrict__ out) {
    float acc = 0.0f;
    const int stride = gridDim.x * blockDim.x;
    for (int idx = blockIdx.x * blockDim.x + threadIdx.x; idx < NTOT; idx += stride) {
        const float* base;
        int hw, cell;
        float w;
        if (idx < N0)            { base = p0; hw = HW0; cell = idx;            w = 1.0f / N0; }
        else if (idx < N0 + N1)  { base = p1; hw = HW1; cell = idx - N0;       w = 1.0f / N1; }
        else                     { base = p2; hw = HW2; cell = idx - N0 - N1;  w = 1.0f / N2; }
        int b   = cell / hw;
        int rem = cell - b * hw;
        float x = base[(b * 11 + 4) * hw + rem];
        float p = 1.0f / (1.0f + expf(-x));
        float log1mp = fmaxf(log1pf(-p), -100.0f);
        acc += (-log1mp) * w;
    }
    float tot = block_reduce_sum(acc);
    if (threadIdx.x == 0) atomicAdd(out, tot);
}

// Pass 2: for each (target, level), dedup via bitmask; first setter adds
// the correction (-logp + log1mp)/N_level  (replaces t=0 term by t=1 term).
__global__ void scatter_corr_kernel(const float* __restrict__ p0,
                                    const float* __restrict__ p1,
                                    const float* __restrict__ p2,
                                    const float* __restrict__ tgt,
                                    unsigned int* __restrict__ bits,
                                    float* __restrict__ out) {
    int tid = blockIdx.x * blockDim.x + threadIdx.x;
    if (tid >= 3 * NTGT) return;
    int level = tid / NTGT;
    int t     = tid - level * NTGT;

    float bf = tgt[t * 6 + 0];
    float tx = tgt[t * 6 + 1];
    float ty = tgt[t * 6 + 2];

    const float* base;
    int h, w, wordbase;
    float wgt;
    if (level == 0)      { h = H0; w = H0; base = p0; wordbase = 0;              wgt = 1.0f / N0; }
    else if (level == 1) { h = H1; w = H1; base = p1; wordbase = N0 / 32;        wgt = 1.0f / N1; }
    else                 { h = H2; w = H2; base = p2; wordbase = (N0 + N1) / 32; wgt = 1.0f / N2; }

    int gx = (int)(tx * (float)w);   // trunc toward zero, same as astype(int32)
    int gy = (int)(ty * (float)h);
    bool valid = (bf < (float)BS_) && (gx >= 0) && (gx < w) && (gy >= 0) && (gy < h);
    if (!valid) return;
    int b = (int)bf;
    if (b < 0) return; // mode='drop' semantics

    int cell = (b * h + gy) * w + gx;
    unsigned bit = 1u << (cell & 31);
    unsigned old = atomicOr(&bits[wordbase + (cell >> 5)], bit);
    if (old & bit) return;  // duplicate target cell — set semantics

    float x = base[(b * 11 + 4) * h * w + gy * w + gx];
    float p = 1.0f / (1.0f + expf(-x));
    float logp   = fmaxf(logf(p),     -100.0f);
    float log1mp = fmaxf(log1pf(-p),  -100.0f);
    atomicAdd(out, (-logp + log1mp) * wgt);
}

extern "C" void kernel_launch(void* const* d_in, const int* in_sizes, int n_in,
                              void* d_out, int out_size, void* d_ws, size_t ws_size,
                              hipStream_t stream) {
    const float* p0  = (const float*)d_in[0];
    const float* p1  = (const float*)d_in[1];
    const float* p2  = (const float*)d_in[2];
    const float* tgt = (const float*)d_in[3];
    float* out = (float*)d_out;
    unsigned int* bits = (unsigned int*)d_ws;

    // zero output scalar and dedup bitmask (must happen every call — graph replays)
    hipMemsetAsync(out, 0, sizeof(float), stream);
    hipMemsetAsync(bits, 0, BITS_BYTES, stream);

    base_sum_kernel<<<2048, 256, 0, stream>>>(p0, p1, p2, out);

    int corrThreads = 3 * NTGT;
    scatter_corr_kernel<<<(corrThreads + 255) / 256, 256, 0, stream>>>(
        p0, p1, p2, tgt, bits, out);
}

// Round 2
// 41.767 us; speedup vs baseline: 1.1471x; 1.1471x over previous
//
#include <hip/hip_runtime.h>
#include <math.h>

constexpr int BS_   = 64;
constexpr int NTGT  = 5000;
constexpr int H0 = 160, H1 = 80, H2 = 40;
constexpr int HW0 = H0 * H0;          // 25600
constexpr int HW1 = H1 * H1;          // 6400
constexpr int HW2 = H2 * H2;          // 1600
constexpr int N0 = BS_ * HW0;         // 1,638,400
constexpr int N1 = BS_ * HW1;         // 409,600
constexpr int N2 = BS_ * HW2;         // 102,400
constexpr int Q0 = N0 / 4, Q1 = N1 / 4, Q2 = N2 / 4;
constexpr int QTOT = Q0 + Q1 + Q2;    // 537,600 float4 elements
constexpr int NBLK = 2048;
constexpr int TPB  = 256;
constexpr int TBL  = 8192;            // LDS hash slots (32 KB), > NTGT

__device__ __forceinline__ float bce_t0(float x) {
    // -max(log1p(-sigmoid(x)), -100)
    float p = 1.0f / (1.0f + expf(-x));
    return -fmaxf(log1pf(-p), -100.0f);
}

// Fused: grid-stride base reduction over all cells (t=0 term), plus blocks
// 0..2 compute the per-level target corrections with LDS hash dedup.
// Each block plain-stores its partial into ws[blockIdx.x] — no init needed.
__global__ __launch_bounds__(TPB) void fused_kernel(
        const float* __restrict__ p0, const float* __restrict__ p1,
        const float* __restrict__ p2, const float* __restrict__ tgt,
        float* __restrict__ ws) {
    __shared__ unsigned tbl[TBL];
    __shared__ float red[TPB / 64];

    float acc = 0.0f;

    // ---- base pass: t=0 BCE term over channel 4 of every level ----
    const int stride = gridDim.x * blockDim.x;
    for (int idx = blockIdx.x * blockDim.x + threadIdx.x; idx < QTOT; idx += stride) {
        const float* base;
        int qhw, q;
        float w;
        if (idx < Q0)            { base = p0; qhw = HW0 / 4; q = idx;           w = 1.0f / N0; }
        else if (idx < Q0 + Q1)  { base = p1; qhw = HW1 / 4; q = idx - Q0;      w = 1.0f / N1; }
        else                     { base = p2; qhw = HW2 / 4; q = idx - Q0 - Q1; w = 1.0f / N2; }
        int b   = q / qhw;                     // constexpr divisor -> magic mul
        int rem = q - b * qhw;
        const float4 x4 = *reinterpret_cast<const float4*>(
            base + (size_t)(b * 11 + 4) * (size_t)(qhw * 4) + (size_t)rem * 4);
        float s = bce_t0(x4.x) + bce_t0(x4.y) + bce_t0(x4.z) + bce_t0(x4.w);
        acc += s * w;
    }

    // ---- correction pass: blocks 0..2 own one level each ----
    if (blockIdx.x < 3) {
        const int level = blockIdx.x;
        for (int i = threadIdx.x; i < TBL; i += blockDim.x) tbl[i] = 0xFFFFFFFFu;
        __syncthreads();

        const float* base;
        int h;
        float wgt;
        if (level == 0)      { base = p0; h = H0; wgt = 1.0f / N0; }
        else if (level == 1) { base = p1; h = H1; wgt = 1.0f / N1; }
        else                 { base = p2; h = H2; wgt = 1.0f / N2; }

        for (int t = threadIdx.x; t < NTGT; t += blockDim.x) {
            float bf = tgt[t * 6 + 0];
            float tx = tgt[t * 6 + 1];
            float ty = tgt[t * 6 + 2];
            int gx = (int)(tx * (float)h);   // trunc, matches astype(int32)
            int gy = (int)(ty * (float)h);
            if (!(bf < (float)BS_ && gx >= 0 && gx < h && gy >= 0 && gy < h)) continue;
            int b = (int)bf;
            if (b < 0) continue;             // mode='drop'

            unsigned cell = (unsigned)((b * h + gy) * h + gx);
            unsigned slot = (cell * 2654435761u) >> 19;   // top 13 bits -> [0,8192)
            bool isNew = false;
            while (true) {
                unsigned prev = atomicCAS(&tbl[slot], 0xFFFFFFFFu, cell);
                if (prev == 0xFFFFFFFFu) { isNew = true; break; }
                if (prev == cell) break;     // duplicate target cell — set semantics
                slot = (slot + 1) & (TBL - 1);
            }
            if (isNew) {
                float x = base[(size_t)(b * 11 + 4) * (size_t)(h * h) + gy * h + gx];
                float p = 1.0f / (1.0f + expf(-x));
                float logp   = fmaxf(logf(p),    -100.0f);
                float log1mp = fmaxf(log1pf(-p), -100.0f);
                acc += (-logp + log1mp) * wgt;   // replace t=0 term by t=1 term
            }
        }
    }

    // ---- block reduce, plain store of partial ----
    #pragma unroll
    for (int off = 32; off > 0; off >>= 1) acc += __shfl_down(acc, off, 64);
    int lane = threadIdx.x & 63;
    int wid  = threadIdx.x >> 6;
    __syncthreads();                    // tbl/red reuse barrier (uniform)
    if (lane == 0) red[wid] = acc;
    __syncthreads();
    if (threadIdx.x == 0) {
        float tot = 0.0f;
        #pragma unroll
        for (int i = 0; i < TPB / 64; ++i) tot += red[i];
        ws[blockIdx.x] = tot;
    }
}

__global__ __launch_bounds__(TPB) void final_reduce(const float* __restrict__ ws,
                                                    float* __restrict__ out) {
    __shared__ float red[TPB / 64];
    float acc = 0.0f;
    for (int i = threadIdx.x; i < NBLK; i += blockDim.x) acc += ws[i];
    #pragma unroll
    for (int off = 32; off > 0; off >>= 1) acc += __shfl_down(acc, off, 64);
    int lane = threadIdx.x & 63;
    int wid  = threadIdx.x >> 6;
    if (lane == 0) red[wid] = acc;
    __syncthreads();
    if (threadIdx.x == 0) {
        float tot = 0.0f;
        #pragma unroll
        for (int i = 0; i < TPB / 64; ++i) tot += red[i];
        out[0] = tot;
    }
}

extern "C" void kernel_launch(void* const* d_in, const int* in_sizes, int n_in,
                              void* d_out, int out_size, void* d_ws, size_t ws_size,
                              hipStream_t stream) {
    const float* p0  = (const float*)d_in[0];
    const float* p1  = (const float*)d_in[1];
    const float* p2  = (const float*)d_in[2];
    const float* tgt = (const float*)d_in[3];
    float* out = (float*)d_out;
    float* ws  = (float*)d_ws;

    fused_kernel<<<NBLK, TPB, 0, stream>>>(p0, p1, p2, tgt, ws);
    final_reduce<<<1, TPB, 0, stream>>>(ws, out);
}